// Round 14
// baseline (345.467 us; speedup 1.0000x reference)
//
#include <hip/hip_runtime.h>

// ---- problem constants (from reference) ----
#define N_LANEC  20000
#define N_AGENTC 4000
#define PTS      20
#define FD       8
#define HD       128
#define E_LLC    640000
#define E_AAC    128000
#define E_LAC    200000

#define CAP_LL 80     // deg ~ Binom(640k, 1/20k): mean 32; P(>80) ~ 0
#define CAP_AA 80     // mean 32
#define CAP_LA 112    // mean 50

typedef unsigned short u16;
typedef unsigned int   u32;
typedef __attribute__((ext_vector_type(8))) short short8;   // 8 bf16 (4 VGPRs)
typedef __attribute__((ext_vector_type(4))) float f32x4;    // MFMA C/D

__device__ __forceinline__ float bf2f(u16 u) {
    union { u32 i; float f; } c; c.i = ((u32)u) << 16; return c.f;
}
__device__ __forceinline__ u16 f2bf(float f) {
    union { float f; u32 i; } c; c.f = f;
    u32 r = c.i + 0x7FFFu + ((c.i >> 16) & 1u);   // RNE
    return (u16)(r >> 16);
}
__device__ __forceinline__ float ldf(const void* p, size_t i, int isf) {
    return isf ? ((const float*)p)[i] : bf2f(((const u16*)p)[i]);
}

// per-block input dtype detection (round-4 verified; fp32 on this dataset)
__device__ __forceinline__ int detect_isf(const u32* x) {
    __shared__ int scnt;
    if (threadIdx.x == 0) scnt = 0;
    __syncthreads();
    u32 w = x[threadIdx.x & 255];
    int e = (int)((w >> 7) & 0xFFu);
    int ok = (e == 0) || (e >= 100 && e <= 140);
    atomicAdd(&scnt, ok);
    __syncthreads();
    return (scnt >= 200) ? 0 : 1;   // 1 = fp32
}

#define NE_TOT (E_LLC + E_AAC + E_LAC)

// ---------------------------------------------------------------------------
// K1: weight prep + dflag only (small, ~15 µs).
// segs 0..9:  B-frag swizzle; klims: 256 for the three 2HxH w1 mats
// segs 10,11: encoder w1 (8x128) as K=32 B-frag, rows 8..31 zero
// segs 12..23: biases -> bf16 linear
// ---------------------------------------------------------------------------
struct SwzSrc { const void* p[24]; };
#define SWZ_TOTAL   222720
#define SWZ_BLOCKS  870           // == SWZ_TOTAL/256 exactly
__global__ __launch_bounds__(256) void swz_kernel(
    SwzSrc s, u16* __restrict__ dst, const u32* __restrict__ lane_pts,
    int* __restrict__ dflag)
{
    const int tid = threadIdx.x;
    const int isf = detect_isf(lane_pts);
    if (blockIdx.x == 0 && tid == 0) *dflag = isf;

    const int sizes[24] = {16384,16384,16384,16384,32768,16384,32768,16384,32768,16384,
                           4096,4096, 128,128,128,128,128,128,128,128,128,128,128,128};
    const int kss[12]   = {2,2,2,2,3,2,3,2,3,2,0,0};
    const int klims[12] = {128,128,128,128,256,128,256,128,256,128,8,8};
    int idx = blockIdx.x * 256 + tid;
    int seg = 0, rem = idx;
    while (rem >= sizes[seg]) { rem -= sizes[seg]; seg++; }
    if (seg >= 12) { dst[idx] = f2bf(ldf(s.p[seg], rem, isf)); return; }
    const int klim = klims[seg];
    int kshift = kss[seg];
    int j    = rem & 7;
    int lane = (rem >> 3) & 63;
    int t2   = rem >> 9;
    int ks   = t2 & ((1 << kshift) - 1);
    int nt   = t2 >> kshift;
    int k = ks * 32 + ((lane >> 4) << 3) + j;
    int n = nt * 16 + (lane & 15);
    dst[idx] = (k < klim) ? f2bf(ldf(s.p[seg], (size_t)k * HD + n, isf)) : (u16)0;
}

// ---------------------------------------------------------------------------
// K2: bucket fill (blocks 0..3781, latency-bound) + encoders (blocks 3782..,
// MFMA-bound) — r12 evidence shows these overlap when co-resident.
// deg zeroed by hipMemsetAsync before K1. No count pass, no scan.
// Encoder: 2 barriers; L1/L3 A-frags in registers; running-max L2 epilogue.
// ---------------------------------------------------------------------------
#define FILL_BLOCKS ((NE_TOT + 255) / 256)   // 3782
#define ENC_BLOCKS ((N_LANEC + N_AGENTC) / 4)   // 6000
struct FillEncArgs {
    const int *e_ll, *e_aa, *e_la;
    int *deg;                      // [0,20000) ll, [20000,24000) aa, [24000,28000) la
    u16 *col_ll, *col_aa, *col_la;
    const void* x0; const void* x1;
    const u16 *w1a, *b1a, *w2a, *b2a, *w3a, *b3a;   // lane set (swizzled/bf16)
    const u16 *w1b, *b1b, *w2b, *b2b, *w3b, *b3b;   // agent set
    u16 *out0, *out1;
    const int* dflag;
};
__global__ __launch_bounds__(256) void fill_enc_kernel(FillEncArgs fa)
{
    const int tid = threadIdx.x;
    if (blockIdx.x < FILL_BLOCKS) {       // ---- bucket fill part ----
        int e = blockIdx.x * 256 + tid;
        if (e < E_LLC) {
            int d = fa.e_ll[E_LLC + e];
            int p = atomicAdd(&fa.deg[d], 1);
            if (p < CAP_LL) fa.col_ll[(size_t)d * CAP_LL + p] = (u16)fa.e_ll[e];
        } else if (e < E_LLC + E_AAC) {
            int i = e - E_LLC;
            int d = fa.e_aa[E_AAC + i];
            int p = atomicAdd(&fa.deg[N_LANEC + d], 1);
            if (p < CAP_AA) fa.col_aa[(size_t)d * CAP_AA + p] = (u16)fa.e_aa[i];
        } else if (e < NE_TOT) {
            int i = e - E_LLC - E_AAC;
            int d = fa.e_la[E_LAC + i];
            int p = atomicAdd(&fa.deg[N_LANEC + N_AGENTC + d], 1);
            if (p < CAP_LA) fa.col_la[(size_t)d * CAP_LA + p] = (u16)fa.e_la[i];
        }
        return;
    }

    // ---- encoder part ----
    const int NT = 4;                                  // nodes/block, M = 80
    __shared__ __align__(16) u16 a_lds[NT * PTS][HD + 8];  // h1 bf16, 21.8 KB
    __shared__ int msI[NT][HD];                        // max-over-t bits, 2 KB

    const int bid = blockIdx.x - FILL_BLOCKS;
    const int isf = *fa.dflag;
    const int isLane = (bid < N_LANEC / 4);
    const void* x  = isLane ? fa.x0 : fa.x1;
    const u16* w1s = isLane ? fa.w1a : fa.w1b;
    const u16* b1  = isLane ? fa.b1a : fa.b1b;
    const u16* w2s = isLane ? fa.w2a : fa.w2b;
    const u16* b2  = isLane ? fa.b2a : fa.b2b;
    const u16* w3s = isLane ? fa.w3a : fa.w3b;
    const u16* b3  = isLane ? fa.b3a : fa.b3b;
    u16* out = isLane ? fa.out0 : fa.out1;
    const int n0 = (isLane ? bid : bid - N_LANEC / 4) * NT;

    const int lane = tid & 63;
    const int wv   = tid >> 6;
    const int l15  = lane & 15;
    const int quad = lane >> 4;

    for (int idx = tid; idx < NT * HD; idx += 256) ((int*)msI)[idx] = 0;

    // ---- L1 A-frags in registers ----
    short8 afr[5];
    #pragma unroll
    for (int mt = 0; mt < 5; mt++) afr[mt] = (short8){0,0,0,0,0,0,0,0};
    if (quad == 0) {
        #pragma unroll
        for (int mt = 0; mt < 5; mt++) {
            const int m  = mt * 16 + l15;
            const int nn = m / 20;
            const size_t xb = ((size_t)n0 * 20 + m) * 8;
            const size_t rb = (((size_t)(n0 + nn)) * 20 + 19) * 8;
            float f[8];
            if (isf) {
                const float* xf = (const float*)x;
                const float4 lo = *(const float4*)(xf + xb);
                const float4 hi = *(const float4*)(xf + xb + 4);
                f[0] = lo.x - xf[rb]; f[1] = lo.y - xf[rb + 1];
                f[2] = lo.z; f[3] = lo.w;
                f[4] = hi.x; f[5] = hi.y; f[6] = hi.z; f[7] = hi.w;
            } else {
                const u16* xu = (const u16*)x;
                #pragma unroll
                for (int k = 0; k < 8; k++) f[k] = bf2f(xu[xb + k]);
                f[0] -= bf2f(xu[rb]); f[1] -= bf2f(xu[rb + 1]);
            }
            short8 av;
            #pragma unroll
            for (int k = 0; k < 8; k++) av[k] = (short)f2bf(f[k]);
            afr[mt] = av;
        }
    }
    // ---- layer 1 MFMA (K=32, B rows 8..31 zero), bias in acc init ----
    #pragma unroll
    for (int nt2 = 0; nt2 < 2; nt2++) {
        const int ntg = wv * 2 + nt2;
        const float b1v = bf2f(b1[ntg * 16 + l15]);
        const short8 bf = *(const short8*)&w1s[(((size_t)ntg) * 64 + lane) * 8];
        #pragma unroll
        for (int mt = 0; mt < 5; mt++) {
            f32x4 c = { b1v, b1v, b1v, b1v };
            c = __builtin_amdgcn_mfma_f32_16x16x32_bf16(afr[mt], bf, c, 0, 0, 0);
            #pragma unroll
            for (int r = 0; r < 4; r++)
                a_lds[mt * 16 + quad * 4 + r][ntg * 16 + l15] = f2bf(fmaxf(c[r], 0.f));
        }
    }
    __syncthreads();                                   // barrier 1

    // ---- layer 2 MFMA; running-max epilogue, flush on node transition ----
    short8 bfr[2][4];
    float b2v[2];
    #pragma unroll
    for (int nt2 = 0; nt2 < 2; nt2++) {
        const int ntg = wv * 2 + nt2;
        b2v[nt2] = bf2f(b2[ntg * 16 + l15]);
        #pragma unroll
        for (int ks = 0; ks < 4; ks++)
            bfr[nt2][ks] = *(const short8*)&w2s[(((size_t)(ntg * 4 + ks)) * 64 + lane) * 8];
    }
    const int col0 = (wv * 2 + 0) * 16 + l15;
    const int col1 = (wv * 2 + 1) * 16 + l15;
    float rm0 = 0.f, rm1 = 0.f;
    int curnode = 0;
    for (int mt = 0; mt < 5; mt++) {
        short8 af[4];
        #pragma unroll
        for (int ks = 0; ks < 4; ks++)
            af[ks] = *(const short8*)&a_lds[mt * 16 + l15][ks * 32 + quad * 8];
        f32x4 c0 = { b2v[0], b2v[0], b2v[0], b2v[0] };
        f32x4 c1 = { b2v[1], b2v[1], b2v[1], b2v[1] };
        #pragma unroll
        for (int ks = 0; ks < 4; ks++) {
            c0 = __builtin_amdgcn_mfma_f32_16x16x32_bf16(af[ks], bfr[0][ks], c0, 0, 0, 0);
            c1 = __builtin_amdgcn_mfma_f32_16x16x32_bf16(af[ks], bfr[1][ks], c1, 0, 0, 0);
        }
        #pragma unroll
        for (int r = 0; r < 4; r++) {
            const int m = mt * 16 + quad * 4 + r;
            const int nd = m / PTS;
            if (nd != curnode) {
                atomicMax(&msI[curnode][col0], __float_as_int(rm0));
                atomicMax(&msI[curnode][col1], __float_as_int(rm1));
                rm0 = 0.f; rm1 = 0.f; curnode = nd;
            }
            rm0 = fmaxf(rm0, c0[r]);
            rm1 = fmaxf(rm1, c1[r]);
        }
    }
    atomicMax(&msI[curnode][col0], __float_as_int(rm0));
    atomicMax(&msI[curnode][col1], __float_as_int(rm1));
    __syncthreads();                                   // barrier 2

    // ---- layer 3: A-frags converted in-register from msI ----
    short8 a3[4];
    #pragma unroll
    for (int ks = 0; ks < 4; ks++) {
        short8 av = (short8){0,0,0,0,0,0,0,0};
        if (l15 < NT) {
            const int* row = &msI[l15][ks * 32 + quad * 8];
            #pragma unroll
            for (int k = 0; k < 8; k++) av[k] = (short)f2bf(__int_as_float(row[k]));
        }
        a3[ks] = av;
    }
    #pragma unroll
    for (int nt2 = 0; nt2 < 2; nt2++) {
        const int ntg = wv * 2 + nt2;
        const float b3v = bf2f(b3[ntg * 16 + l15]);
        f32x4 c = { b3v, b3v, b3v, b3v };
        #pragma unroll
        for (int ks = 0; ks < 4; ks++) {
            short8 b = *(const short8*)&w3s[(((size_t)(ntg * 4 + ks)) * 64 + lane) * 8];
            c = __builtin_amdgcn_mfma_f32_16x16x32_bf16(a3[ks], b, c, 0, 0, 0);
        }
        #pragma unroll
        for (int r = 0; r < 4; r++) {
            const int row = quad * 4 + r;
            if (row < NT)
                out[(size_t)(n0 + row) * HD + ntg * 16 + l15] = f2bf(fmaxf(c[r], 0.f));
        }
    }
}

// ---------------------------------------------------------------------------
// K3/K4: fused gather + edge-GNN MLP, bucket-CSR (deg + fixed-CAP col).
// ---------------------------------------------------------------------------
template<int SRC_F32, int OUT_BF16>
__device__ __forceinline__ void gnn_body(
    int n0, const u16* __restrict__ node, const void* __restrict__ srcv,
    const u16* __restrict__ col, const int* __restrict__ deg, int cap,
    const u16* __restrict__ w1s, const u16* __restrict__ b1,
    const u16* __restrict__ w2s, const u16* __restrict__ b2,
    void* __restrict__ outv)
{
    __shared__ __align__(16) u16 cats[16][2 * HD + 8];
    __shared__ __align__(16) u16 hb[16][HD + 8];
    const int tid  = threadIdx.x;
    const int lane = tid & 63;
    const int wv   = tid >> 6;
    const int l15  = lane & 15;
    const int quad = lane >> 4;

    const u32* node32 = (const u32*)node;
    for (int idx = tid; idx < 16 * 64; idx += 256) {
        int nn = idx >> 6, k2 = idx & 63;
        *(u32*)&cats[nn][k2 * 2] = node32[(size_t)(n0 + nn) * 64 + k2];
    }
    const int h = tid >> 7;
    const int j = tid & 127;
    const float* srcf = (const float*)srcv;
    const u16*   srcu = (const u16*)srcv;
    for (int q = 0; q < 8; q++) {
        const int dn = h * 8 + q;
        const int d  = n0 + dn;
        const int dv = deg[d];
        const int cnt = min(dv, cap);
        const u16* cb = col + (size_t)d * cap;
        float acc = 0.f;
        int e = 0;
        for (; e + 4 <= cnt; e += 4) {
            const int r0 = (int)cb[e], r1 = (int)cb[e + 1];
            const int r2 = (int)cb[e + 2], r3 = (int)cb[e + 3];
            if (SRC_F32) {
                acc += srcf[(size_t)r0 * HD + j] + srcf[(size_t)r1 * HD + j]
                     + srcf[(size_t)r2 * HD + j] + srcf[(size_t)r3 * HD + j];
            } else {
                acc += bf2f(srcu[(size_t)r0 * HD + j]) + bf2f(srcu[(size_t)r1 * HD + j])
                     + bf2f(srcu[(size_t)r2 * HD + j]) + bf2f(srcu[(size_t)r3 * HD + j]);
            }
        }
        for (; e < cnt; e++) {
            const int r = (int)cb[e];
            acc += SRC_F32 ? srcf[(size_t)r * HD + j] : bf2f(srcu[(size_t)r * HD + j]);
        }
        cats[dn][HD + j] = f2bf(acc / fmaxf((float)dv, 1.f));
    }
    __syncthreads();

    #pragma unroll
    for (int nt2 = 0; nt2 < 2; nt2++) {
        const int ntg = wv * 2 + nt2;
        const float b1v = bf2f(b1[ntg * 16 + l15]);
        f32x4 c = { b1v, b1v, b1v, b1v };
        #pragma unroll
        for (int ks = 0; ks < 8; ks++) {
            short8 a = *(const short8*)&cats[l15][ks * 32 + quad * 8];
            short8 b = *(const short8*)&w1s[(((size_t)(ntg * 8 + ks)) * 64 + lane) * 8];
            c = __builtin_amdgcn_mfma_f32_16x16x32_bf16(a, b, c, 0, 0, 0);
        }
        #pragma unroll
        for (int r = 0; r < 4; r++)
            hb[quad * 4 + r][ntg * 16 + l15] = f2bf(fmaxf(c[r], 0.f));
    }
    __syncthreads();

    #pragma unroll
    for (int nt2 = 0; nt2 < 2; nt2++) {
        const int ntg = wv * 2 + nt2;
        const float b2v = bf2f(b2[ntg * 16 + l15]);
        f32x4 c = { b2v, b2v, b2v, b2v };
        #pragma unroll
        for (int ks = 0; ks < 4; ks++) {
            short8 a = *(const short8*)&hb[l15][ks * 32 + quad * 8];
            short8 b = *(const short8*)&w2s[(((size_t)(ntg * 4 + ks)) * 64 + lane) * 8];
            c = __builtin_amdgcn_mfma_f32_16x16x32_bf16(a, b, c, 0, 0, 0);
        }
        #pragma unroll
        for (int r = 0; r < 4; r++) {
            const int row = quad * 4 + r;
            size_t o = (size_t)(n0 + row) * HD + ntg * 16 + l15;
            float res = bf2f(node[o]) + fmaxf(c[r], 0.f);
            if (OUT_BF16) ((u16*)outv)[o] = f2bf(res);
            else          ((float*)outv)[o] = res;
        }
    }
}

struct Gnn2Args {
    const u16* node_ll; const u16* col_ll; const int* deg_ll;
    const u16 *w1_ll, *b1_ll, *w2_ll, *b2_ll; float* out_ll;
    const u16* node_aa; const u16* col_aa; const int* deg_aa;
    const u16 *w1_aa, *b1_aa, *w2_aa, *b2_aa; u16* out_aa;
};
__global__ __launch_bounds__(256) void gnn2_kernel(Gnn2Args a) {
    if (blockIdx.x < N_LANEC / 16)
        gnn_body<0, 0>(blockIdx.x * 16, a.node_ll, a.node_ll, a.col_ll, a.deg_ll, CAP_LL,
                       a.w1_ll, a.b1_ll, a.w2_ll, a.b2_ll, a.out_ll);
    else
        gnn_body<0, 1>((blockIdx.x - N_LANEC / 16) * 16, a.node_aa, a.node_aa,
                       a.col_aa, a.deg_aa, CAP_AA,
                       a.w1_aa, a.b1_aa, a.w2_aa, a.b2_aa, a.out_aa);
}
__global__ __launch_bounds__(256) void gnn_la_kernel(
    const u16* node, const float* src, const u16* col, const int* deg,
    const u16* w1s, const u16* b1, const u16* w2s, const u16* b2, float* out) {
    gnn_body<1, 0>(blockIdx.x * 16, node, src, col, deg, CAP_LA, w1s, b1, w2s, b2, out);
}

// ---------------------------------------------------------------------------
extern "C" void kernel_launch(void* const* d_in, const int* in_sizes, int n_in,
                              void* d_out, int out_size, void* d_ws, size_t ws_size,
                              hipStream_t stream)
{
    const void* lane_pts   = d_in[0];
    const void* agent_hist = d_in[1];
    const int* e_ll = (const int*)d_in[2];   // [2][E]: row0 src, row1 dst
    const int* e_aa = (const int*)d_in[3];
    const int* e_la = (const int*)d_in[4];
    const void *lw1 = d_in[5],  *lb1 = d_in[6],  *lw2 = d_in[7],  *lb2 = d_in[8],
               *lw3 = d_in[9],  *lb3 = d_in[10];
    const void *aw1 = d_in[11], *ab1 = d_in[12], *aw2 = d_in[13], *ab2 = d_in[14],
               *aw3 = d_in[15], *ab3 = d_in[16];
    const void *llw1 = d_in[17], *llb1 = d_in[18], *llw2 = d_in[19], *llb2 = d_in[20];
    const void *aaw1 = d_in[21], *aab1 = d_in[22], *aaw2 = d_in[23], *aab2 = d_in[24];
    const void *law1 = d_in[25], *lab1 = d_in[26], *law2 = d_in[27], *lab2 = d_in[28];

    // ---- workspace layout (~11.9 MB, unchanged from r13) ----
    u16* sp = (u16*)d_ws;
    u16* swzbase = sp; sp += SWZ_TOTAL;
    u16* lw2s  = swzbase + 0;
    u16* aw2s  = swzbase + 16384;
    u16* lw3s  = swzbase + 32768;
    u16* aw3s  = swzbase + 49152;
    u16* llw1s = swzbase + 65536;
    u16* llw2s = swzbase + 98304;
    u16* aaw1s = swzbase + 114688;
    u16* aaw2s = swzbase + 147456;
    u16* law1s = swzbase + 163840;
    u16* law2s = swzbase + 196608;
    u16* lw1s  = swzbase + 212992;   // K=32 frag, rows 8..31 zero
    u16* aw1s  = swzbase + 217088;
    u16* lb1b  = swzbase + 221184;
    u16* lb2b  = swzbase + 221312;
    u16* lb3b  = swzbase + 221440;
    u16* ab1b  = swzbase + 221568;
    u16* ab2b  = swzbase + 221696;
    u16* ab3b  = swzbase + 221824;
    u16* llb1b = swzbase + 221952;
    u16* llb2b = swzbase + 222080;
    u16* aab1b = swzbase + 222208;
    u16* aab2b = swzbase + 222336;
    u16* lab1b = swzbase + 222464;
    u16* lab2b = swzbase + 222592;
    int* ip = (int*)sp;                      // 16B aligned
    int* dflag = ip; ip += 4;
    int* deg   = ip; ip += N_LANEC + 2 * N_AGENTC;   // 28000 ints
    u16* hp = (u16*)ip;
    u16* col_ll = hp; hp += (size_t)N_LANEC * CAP_LL;
    u16* col_aa = hp; hp += (size_t)N_AGENTC * CAP_AA;
    u16* col_la = hp; hp += (size_t)N_AGENTC * CAP_LA;
    u16* lane_enc  = hp; hp += (size_t)N_LANEC * HD;
    u16* agent_enc = hp; hp += (size_t)N_AGENTC * HD;
    u16* agent_mid = hp; hp += (size_t)N_AGENTC * HD;

    float* out_lane  = (float*)d_out;
    float* out_agent = (float*)d_out + (size_t)N_LANEC * HD;

    // ---- 0: zero degree counters (stream-ordered, graph-capturable) ----
    hipMemsetAsync(deg, 0, (size_t)(N_LANEC + 2 * N_AGENTC) * sizeof(int), stream);

    // ---- K1: weight prep + dflag (small) ----
    SwzSrc ss;
    ss.p[0] = lw2;  ss.p[1] = aw2;  ss.p[2] = lw3;  ss.p[3] = aw3;
    ss.p[4] = llw1; ss.p[5] = llw2; ss.p[6] = aaw1; ss.p[7] = aaw2;
    ss.p[8] = law1; ss.p[9] = law2; ss.p[10] = lw1; ss.p[11] = aw1;
    ss.p[12] = lb1; ss.p[13] = lb2; ss.p[14] = lb3;
    ss.p[15] = ab1; ss.p[16] = ab2; ss.p[17] = ab3;
    ss.p[18] = llb1; ss.p[19] = llb2; ss.p[20] = aab1; ss.p[21] = aab2;
    ss.p[22] = lab1; ss.p[23] = lab2;
    swz_kernel<<<SWZ_BLOCKS, 256, 0, stream>>>(ss, swzbase, (const u32*)lane_pts, dflag);

    // ---- K2: bucket fill + encoders (merged; latency work overlaps MFMA) ----
    FillEncArgs fa;
    fa.e_ll = e_ll; fa.e_aa = e_aa; fa.e_la = e_la;
    fa.deg = deg;
    fa.col_ll = col_ll; fa.col_aa = col_aa; fa.col_la = col_la;
    fa.x0 = lane_pts; fa.x1 = agent_hist;
    fa.w1a = lw1s; fa.b1a = lb1b; fa.w2a = lw2s; fa.b2a = lb2b; fa.w3a = lw3s; fa.b3a = lb3b;
    fa.w1b = aw1s; fa.b1b = ab1b; fa.w2b = aw2s; fa.b2b = ab2b; fa.w3b = aw3s; fa.b3b = ab3b;
    fa.out0 = lane_enc; fa.out1 = agent_enc;
    fa.dflag = dflag;
    fill_enc_kernel<<<FILL_BLOCKS + ENC_BLOCKS, 256, 0, stream>>>(fa);

    // ---- K3: ll + aa GNN with fused bucket gather ----
    Gnn2Args ga;
    ga.node_ll = lane_enc;  ga.col_ll = col_ll; ga.deg_ll = deg;
    ga.w1_ll = llw1s; ga.b1_ll = llb1b; ga.w2_ll = llw2s; ga.b2_ll = llb2b; ga.out_ll = out_lane;
    ga.node_aa = agent_enc; ga.col_aa = col_aa; ga.deg_aa = deg + N_LANEC;
    ga.w1_aa = aaw1s; ga.b1_aa = aab1b; ga.w2_aa = aaw2s; ga.b2_aa = aab2b; ga.out_aa = agent_mid;
    gnn2_kernel<<<(N_LANEC + N_AGENTC) / 16, 256, 0, stream>>>(ga);

    // ---- K4: lane->agent GNN, gather from final lane (f32) ----
    gnn_la_kernel<<<N_AGENTC / 16, 256, 0, stream>>>(
        agent_mid, out_lane, col_la, deg + N_LANEC + N_AGENTC,
        law1s, lab1b, law2s, lab2b, out_agent);
}